// Round 3
// baseline (73.507 us; speedup 1.0000x reference)
//
#include <hip/hip_runtime.h>
#include <hip/hip_bf16.h>

// Plane2Depth: per input pixel compute (p,q,r,s) = W @ feat[b,:,h,w],
// then write a 4x4 upsampled output block of 1/max((p*u + q*v + r)*s, 0.1).
// The norm in the reference cancels exactly (epsilon included):
// (p/n*u + q/n*v + r/n)*(s*n) == (p*u + q*v + r)*s  -> no sqrt needed.
//
// Round 3: native ext_vector float4 for nontemporal stores (HIP_vector_type
// is rejected by __builtin_nontemporal_store); 2 pixels/thread; v_rcp_f32.

#define IN_H 192
#define IN_W 192
#define NBATCH 16
#define UPF 4
#define OUT_H (IN_H * UPF)
#define OUT_W (IN_W * UPF)
#define NPIX (IN_H * IN_W)          // 36864
#define NPAIR (NPIX / 2)            // 18432 pixel-pairs per batch image

typedef float f32x4 __attribute__((ext_vector_type(4)));
typedef float f32x2 __attribute__((ext_vector_type(2)));

__global__ __launch_bounds__(256) void plane2depth_kernel(
    const float* __restrict__ feat,   // (16, 4, 192, 192)
    const float* __restrict__ Wm,     // (4, 4) row-major
    float* __restrict__ out)          // (16, 1, 768, 768)
{
    int t = blockIdx.x * blockDim.x + threadIdx.x;   // one thread per 2 adjacent pixels
    int b  = t / NPAIR;
    int pr = t - b * NPAIR;
    int hw = pr * 2;                 // even pixel index within the image
    int h  = hw / IN_W;
    int w  = hw - h * IN_W;          // even

    // 8B/lane coalesced channel loads for both pixels.
    const float* f = feat + (size_t)b * 4 * NPIX + hw;
    f32x2 c0 = *reinterpret_cast<const f32x2*>(f);
    f32x2 c1 = *reinterpret_cast<const f32x2*>(f + NPIX);
    f32x2 c2 = *reinterpret_cast<const f32x2*>(f + 2 * NPIX);
    f32x2 c3 = *reinterpret_cast<const f32x2*>(f + 3 * NPIX);

    // W is wave-uniform -> scalar loads.
    float w00 = Wm[0],  w01 = Wm[1],  w02 = Wm[2],  w03 = Wm[3];
    float w10 = Wm[4],  w11 = Wm[5],  w12 = Wm[6],  w13 = Wm[7];
    float w20 = Wm[8],  w21 = Wm[9],  w22 = Wm[10], w23 = Wm[11];
    float w30 = Wm[12], w31 = Wm[13], w32 = Wm[14], w33 = Wm[15];

    // matvec for both pixels
    float p0 = w00*c0.x + w01*c1.x + w02*c2.x + w03*c3.x;
    float q0 = w10*c0.x + w11*c1.x + w12*c2.x + w13*c3.x;
    float r0 = w20*c0.x + w21*c1.x + w22*c2.x + w23*c3.x;
    float s0 = w30*c0.x + w31*c1.x + w32*c2.x + w33*c3.x;
    float p1 = w00*c0.y + w01*c1.y + w02*c2.y + w03*c3.y;
    float q1 = w10*c0.y + w11*c1.y + w12*c2.y + w13*c3.y;
    float r1 = w20*c0.y + w21*c1.y + w22*c2.y + w23*c3.y;
    float s1 = w30*c0.y + w31*c1.y + w32*c2.y + w33*c3.y;

    // u_j = v_j = (j - 1.5) / 4
    const float uv[4] = {-0.375f, -0.125f, 0.125f, 0.375f};
    float pu0[4], pu1[4];
#pragma unroll
    for (int j = 0; j < 4; ++j) { pu0[j] = p0 * uv[j]; pu1[j] = p1 * uv[j]; }

    float* o = out + (size_t)b * OUT_H * OUT_W + (size_t)(UPF * h) * OUT_W + UPF * w;

#pragma unroll
    for (int i = 0; i < 4; ++i) {
        float base0 = q0 * uv[i] + r0;
        float base1 = q1 * uv[i] + r1;
        f32x4 a, bb;
        a.x  = __builtin_amdgcn_rcpf(fmaxf((pu0[0] + base0) * s0, 0.1f));
        a.y  = __builtin_amdgcn_rcpf(fmaxf((pu0[1] + base0) * s0, 0.1f));
        a.z  = __builtin_amdgcn_rcpf(fmaxf((pu0[2] + base0) * s0, 0.1f));
        a.w  = __builtin_amdgcn_rcpf(fmaxf((pu0[3] + base0) * s0, 0.1f));
        bb.x = __builtin_amdgcn_rcpf(fmaxf((pu1[0] + base1) * s1, 0.1f));
        bb.y = __builtin_amdgcn_rcpf(fmaxf((pu1[1] + base1) * s1, 0.1f));
        bb.z = __builtin_amdgcn_rcpf(fmaxf((pu1[2] + base1) * s1, 0.1f));
        bb.w = __builtin_amdgcn_rcpf(fmaxf((pu1[3] + base1) * s1, 0.1f));
        f32x4* row = reinterpret_cast<f32x4*>(o + (size_t)i * OUT_W);
        __builtin_nontemporal_store(a,  row);
        __builtin_nontemporal_store(bb, row + 1);
    }
}

extern "C" void kernel_launch(void* const* d_in, const int* in_sizes, int n_in,
                              void* d_out, int out_size, void* d_ws, size_t ws_size,
                              hipStream_t stream) {
    const float* feat = (const float*)d_in[0];
    const float* Wm   = (const float*)d_in[1];
    float* out        = (float*)d_out;

    const int total = NBATCH * NPAIR;            // 294,912 threads
    const int block = 256;
    const int grid  = total / block;             // 1152 blocks (exact)
    plane2depth_kernel<<<grid, block, 0, stream>>>(feat, Wm, out);
}